// Round 1
// 423.389 us; speedup vs baseline: 1.0023x; 1.0023x over previous
//
#include <hip/hip_runtime.h>

#define N_NODES 8192
#define D_IN    128
#define D_OUT   64
#define NSPLIT  8

typedef __attribute__((ext_vector_type(8))) short short8;
typedef __attribute__((ext_vector_type(4))) float f32x4;

// fp32 -> bf16 bits, round-to-nearest-even
__device__ __forceinline__ short f2bf(float f) {
    unsigned u = __builtin_bit_cast(unsigned, f);
    u += 0x7fff + ((u >> 16) & 1);
    return (short)(u >> 16);
}

// ---------------- Kernel 1: dis[i] = rsqrt(rowsum(A[i,:])) ----------------
// One wave per row. 2048 blocks x 256 threads (4 waves). 256 MB streamed.
__global__ __launch_bounds__(256) void k_deg(const float* __restrict__ A,
                                             float* __restrict__ dis) {
    const int wave = threadIdx.x >> 6;
    const int lane = threadIdx.x & 63;
    const int row  = blockIdx.x * 4 + wave;
    const float4* Ar = (const float4*)(A + (size_t)row * N_NODES);
    float s = 0.f;
#pragma unroll
    for (int i = 0; i < 32; ++i) {
        float4 v = Ar[lane + 64 * i];
        s += (v.x + v.y) + (v.z + v.w);
    }
#pragma unroll
    for (int off = 32; off; off >>= 1) s += __shfl_down(s, off, 64);
    if (lane == 0) dis[row] = rsqrtf(s);
}

// ---------------- Kernel 2: G = (diag(dis) * X) @ W, packed in MFMA B-frag order
// Gp layout: [ktile t][ntile u][lane][j] bf16, where for G[k][n]:
//   t = k>>5, quad = (k>>3)&3, j = k&7, u = n>>4, lane = quad*16 + (n&15)
// One block per ktile (32 rows of X). 256 blocks x 256 threads.
__global__ __launch_bounds__(256) void k_gpack(const float* __restrict__ X,
                                               const float* __restrict__ W,
                                               const float* __restrict__ dis,
                                               unsigned short* __restrict__ Gp) {
    __shared__ float Wl[D_IN * D_OUT];     // 32 KB
    __shared__ float Xl[32 * 129];         // padded stride 129 (bank conflicts)
    const int t = blockIdx.x, tid = threadIdx.x;

    // stage W (8192 floats)
    const float4* W4 = (const float4*)W;
    float4* Wl4 = (float4*)Wl;
#pragma unroll
    for (int i = 0; i < 8; ++i) Wl4[tid + 256 * i] = W4[tid + 256 * i];
    // stage X tile (32 x 128 floats = 1024 float4)
    const float4* X4 = (const float4*)(X + (size_t)t * 32 * D_IN);
#pragma unroll
    for (int i = 0; i < 4; ++i) {
        int idx = tid + 256 * i;
        float4 v = X4[idx];
        int r = idx >> 5, c = (idx & 31) * 4;
        float* dst = Xl + r * 129 + c;
        dst[0] = v.x; dst[1] = v.y; dst[2] = v.z; dst[3] = v.w;
    }
    __syncthreads();

    const int kl = tid & 31;             // local k row 0..31
    const int nb = (tid >> 5) * 8;       // 8 consecutive n's
    float acc[8] = {0.f, 0.f, 0.f, 0.f, 0.f, 0.f, 0.f, 0.f};
    const float* xr = Xl + kl * 129;
    for (int d = 0; d < D_IN; ++d) {
        float xv = xr[d];
        const float* wr = Wl + d * D_OUT + nb;
#pragma unroll
        for (int c = 0; c < 8; ++c) acc[c] += xv * wr[c];
    }
    const float scale = dis[t * 32 + kl];
    const int quad = kl >> 3, j = kl & 7;
#pragma unroll
    for (int c = 0; c < 8; ++c) {
        int n = nb + c;
        int u = n >> 4;
        int lanei = quad * 16 + (n & 15);
        Gp[(((size_t)t * 4 + u) * 64 + lanei) * 8 + j] = (unsigned short)f2bf(acc[c] * scale);
    }
}

// ---------------- Kernel 3: h2s[split] = A_chunk @ G  (bf16 MFMA, plain stores)
// Block = 4 waves, each wave owns 16 rows x 64 cols. Grid (128 row-blocks, 8 K-splits).
// Each split writes its own 2 MB slice -> no atomics, no cross-XCD contention.
__global__ __launch_bounds__(256) void k_spmm(const float* __restrict__ A,
                                              const unsigned short* __restrict__ Gp,
                                              float* __restrict__ h2s) {
    const int lane = threadIdx.x & 63;
    const int wave = threadIdx.x >> 6;
    const int quad = lane >> 4;
    const int l15  = lane & 15;
    const int row  = blockIdx.x * 64 + wave * 16 + l15;
    const float* Ar = A + (size_t)row * N_NODES;
    const int kt0 = blockIdx.y * 32;     // 32 ktiles x 32 k = 1024 k per split

    f32x4 acc[4] = {};
    const short8* Gq = (const short8*)Gp;

    for (int kt = kt0; kt < kt0 + 32; ++kt) {
        const float4* pa = (const float4*)(Ar + kt * 32 + quad * 8);
        float4 a0 = pa[0], a1 = pa[1];
        short8 af;
        af[0] = f2bf(a0.x); af[1] = f2bf(a0.y); af[2] = f2bf(a0.z); af[3] = f2bf(a0.w);
        af[4] = f2bf(a1.x); af[5] = f2bf(a1.y); af[6] = f2bf(a1.z); af[7] = f2bf(a1.w);
        const short8* gb = Gq + (size_t)kt * 4 * 64 + lane;
#pragma unroll
        for (int u = 0; u < 4; ++u) {
            short8 bf = gb[u * 64];
            acc[u] = __builtin_amdgcn_mfma_f32_16x16x32_bf16(af, bf, acc[u], 0, 0, 0);
        }
    }
    // C/D layout: row = quad*4 + reg, col = lane&15 (guide §3, m89-verified)
    float* H = h2s + (size_t)blockIdx.y * ((size_t)N_NODES * D_OUT);
    const int r0 = blockIdx.x * 64 + wave * 16 + quad * 4;
#pragma unroll
    for (int u = 0; u < 4; ++u) {
#pragma unroll
        for (int r = 0; r < 4; ++r) {
            H[(size_t)(r0 + r) * D_OUT + u * 16 + l15] = acc[u][r];
        }
    }
}

// ---------------- Kernel 4: out = relu(dis[i] * sum_splits h2s) ----------------
__global__ __launch_bounds__(256) void k_out(const float* __restrict__ h2s,
                                             const float* __restrict__ dis,
                                             float* __restrict__ out) {
    const int idx = blockIdx.x * 256 + threadIdx.x;   // float4 index, 131072 total
    const f32x4* H = (const f32x4*)h2s;
    const int slice = N_NODES * D_OUT / 4;            // 131072 float4 per split
    f32x4 s = H[idx];
#pragma unroll
    for (int p = 1; p < NSPLIT; ++p) s += H[idx + (size_t)p * slice];
    const float sc = dis[idx >> 4];                   // 16 float4 per row of 64
    f32x4 o;
#pragma unroll
    for (int c = 0; c < 4; ++c) o[c] = fmaxf(s[c] * sc, 0.f);
    ((f32x4*)out)[idx] = o;
}

extern "C" void kernel_launch(void* const* d_in, const int* in_sizes, int n_in,
                              void* d_out, int out_size, void* d_ws, size_t ws_size,
                              hipStream_t stream) {
    const float* X = (const float*)d_in[0];   // features [8192,128]
    const float* A = (const float*)d_in[1];   // adjacency [8192,8192]
    const float* W = (const float*)d_in[2];   // weight [128,64]
    float* out = (float*)d_out;

    char* ws = (char*)d_ws;
    float*          dis = (float*)ws;                                  // 32 KB
    unsigned short* Gp  = (unsigned short*)(ws + 32768);               // 1 MB
    float*          h2s = (float*)(ws + 32768 + 1048576);              // 16 MB (8 splits x 2 MB)

    k_deg  <<<N_NODES / 4, 256, 0, stream>>>(A, dis);
    k_gpack<<<N_NODES / 32, 256, 0, stream>>>(X, W, dis, Gp);
    k_spmm <<<dim3(N_NODES / 64, NSPLIT), 256, 0, stream>>>(A, Gp, h2s);
    k_out  <<<(N_NODES * D_OUT / 4) / 256, 256, 0, stream>>>(h2s, dis, out);
}

// Round 3
// 411.042 us; speedup vs baseline: 1.0325x; 1.0300x over previous
//
#include <hip/hip_runtime.h>

#define N_NODES 8192
#define D_IN    128
#define D_OUT   64
#define NSPLIT  8

typedef __attribute__((ext_vector_type(8))) short short8;
typedef __attribute__((ext_vector_type(4))) float f32x4;

// fp32 -> bf16 bits, round-to-nearest-even
__device__ __forceinline__ short f2bf(float f) {
    unsigned u = __builtin_bit_cast(unsigned, f);
    u += 0x7fff + ((u >> 16) & 1);
    return (short)(u >> 16);
}

// ================= NEW PATH =================
// Kernel 1: single pass over A: deg[i] = rowsum, Ap = bf16(A) packed in MFMA
// A-frag order: Ap unit index ((ri*256 + kt)*64 + quad*16 + r) holds
// row (ri*16+r), k = kt*32 + quad*8 + j  (j=0..7), 16 B per unit.
// Block = 256 thr handles one 16-row tile; thread t: r=t>>4, c=t&15.
__global__ __launch_bounds__(256) void k_degpack(const float* __restrict__ A,
                                                 float* __restrict__ deg,
                                                 unsigned short* __restrict__ Ap) {
    const int tid = threadIdx.x;
    const int r = tid >> 4, c = tid & 15;
    const int ri = blockIdx.x;                    // row-tile 0..511
    const int row = ri * 16 + r;
    const f32x4* Ar = (const f32x4*)(A + (size_t)row * N_NODES + c * 8);
    short8* Apv = (short8*)Ap;
    // per-thread unit index: ((ri*256 + m*4 + (c>>2))*64) + (c&3)*16 + r
    const size_t ubase = ((size_t)ri * 256 + (c >> 2)) * 64 + (c & 3) * 16 + r;

    float s = 0.f;
    f32x4 a0 = __builtin_nontemporal_load(Ar);
    f32x4 a1 = __builtin_nontemporal_load(Ar + 1);
#pragma unroll 4
    for (int m = 0; m < 64; ++m) {
        f32x4 b0, b1;
        if (m < 63) {
            b0 = __builtin_nontemporal_load(Ar + (m + 1) * 32);
            b1 = __builtin_nontemporal_load(Ar + (m + 1) * 32 + 1);
        }
        s += (a0[0] + a0[1]) + (a0[2] + a0[3]) + (a1[0] + a1[1]) + (a1[2] + a1[3]);
        short8 p;
        p[0] = f2bf(a0[0]); p[1] = f2bf(a0[1]); p[2] = f2bf(a0[2]); p[3] = f2bf(a0[3]);
        p[4] = f2bf(a1[0]); p[5] = f2bf(a1[1]); p[6] = f2bf(a1[2]); p[7] = f2bf(a1[3]);
        Apv[ubase + (size_t)m * 256] = p;
        a0 = b0; a1 = b1;
    }
    // reduce over c (lanes sharing r are 16 contiguous lanes)
#pragma unroll
    for (int off = 1; off < 16; off <<= 1) s += __shfl_xor(s, off, 64);
    if (c == 0) deg[row] = s;
}

// Kernel 3 (new): h2s[split] = Ap_chunk @ G, pure bf16 MFMA, coalesced A-frags.
__global__ __launch_bounds__(256) void k_spmm_bf16(const unsigned short* __restrict__ Ap,
                                                   const unsigned short* __restrict__ Gp,
                                                   float* __restrict__ h2s) {
    const int lane = threadIdx.x & 63;
    const int wave = threadIdx.x >> 6;
    const int quad = lane >> 4;
    const int l15  = lane & 15;
    const int ri   = blockIdx.x * 4 + wave;       // row-tile (16 rows)
    const int kt0  = blockIdx.y * 32;             // 32 ktiles per split

    const short8* Af = (const short8*)Ap + ((size_t)ri * 256 + kt0) * 64 + lane;
    const short8* Gq = (const short8*)Gp + (size_t)kt0 * 256 + lane;

    f32x4 acc[4] = {};
#pragma unroll 2
    for (int i = 0; i < 32; ++i) {
        short8 af = Af[i * 64];
        const short8* gb = Gq + i * 256;
#pragma unroll
        for (int u = 0; u < 4; ++u) {
            acc[u] = __builtin_amdgcn_mfma_f32_16x16x32_bf16(af, gb[u * 64], acc[u], 0, 0, 0);
        }
    }
    float* H = h2s + (size_t)blockIdx.y * ((size_t)N_NODES * D_OUT);
    const int r0 = ri * 16 + quad * 4;
#pragma unroll
    for (int u = 0; u < 4; ++u)
#pragma unroll
        for (int r = 0; r < 4; ++r)
            H[(size_t)(r0 + r) * D_OUT + u * 16 + l15] = acc[u][r];
}

// ================= SHARED =================
// Kernel 2: G = (diag(rsqrt(deg)) * X) @ W, packed in MFMA B-frag order.
__global__ __launch_bounds__(256) void k_gpack(const float* __restrict__ X,
                                               const float* __restrict__ W,
                                               const float* __restrict__ deg,
                                               unsigned short* __restrict__ Gp) {
    __shared__ float Wl[D_IN * D_OUT];     // 32 KB
    __shared__ float Xl[32 * 129];         // padded stride 129
    const int t = blockIdx.x, tid = threadIdx.x;

    const float4* W4 = (const float4*)W;
    float4* Wl4 = (float4*)Wl;
#pragma unroll
    for (int i = 0; i < 8; ++i) Wl4[tid + 256 * i] = W4[tid + 256 * i];
    const float4* X4 = (const float4*)(X + (size_t)t * 32 * D_IN);
#pragma unroll
    for (int i = 0; i < 4; ++i) {
        int idx = tid + 256 * i;
        float4 v = X4[idx];
        int r = idx >> 5, c = (idx & 31) * 4;
        float* dst = Xl + r * 129 + c;
        dst[0] = v.x; dst[1] = v.y; dst[2] = v.z; dst[3] = v.w;
    }
    __syncthreads();

    const int kl = tid & 31;
    const int nb = (tid >> 5) * 8;
    float acc[8] = {0.f, 0.f, 0.f, 0.f, 0.f, 0.f, 0.f, 0.f};
    const float* xr = Xl + kl * 129;
    for (int d = 0; d < D_IN; ++d) {
        float xv = xr[d];
        const float* wr = Wl + d * D_OUT + nb;
#pragma unroll
        for (int c = 0; c < 8; ++c) acc[c] += xv * wr[c];
    }
    const float scale = rsqrtf(deg[t * 32 + kl]);
    const int quad = kl >> 3, j = kl & 7;
#pragma unroll
    for (int c = 0; c < 8; ++c) {
        int n = nb + c;
        int u = n >> 4;
        int lanei = quad * 16 + (n & 15);
        Gp[(((size_t)t * 4 + u) * 64 + lanei) * 8 + j] = (unsigned short)f2bf(acc[c] * scale);
    }
}

// Kernel 4: out = relu(rsqrt(deg[i]) * sum_splits h2s)
__global__ __launch_bounds__(256) void k_out(const float* __restrict__ h2s,
                                             const float* __restrict__ deg,
                                             float* __restrict__ out) {
    const int idx = blockIdx.x * 256 + threadIdx.x;   // float4 index, 131072 total
    const f32x4* H = (const f32x4*)h2s;
    const int slice = N_NODES * D_OUT / 4;
    f32x4 s = H[idx];
#pragma unroll
    for (int p = 1; p < NSPLIT; ++p) s += H[idx + (size_t)p * slice];
    const float sc = rsqrtf(deg[idx >> 4]);
    f32x4 o;
#pragma unroll
    for (int c = 0; c < 4; ++c) o[c] = fmaxf(s[c] * sc, 0.f);
    ((f32x4*)out)[idx] = o;
}

// ================= OLD PATH (fallback if workspace too small) =================
__global__ __launch_bounds__(256) void k_deg(const float* __restrict__ A,
                                             float* __restrict__ deg) {
    const int wave = threadIdx.x >> 6;
    const int lane = threadIdx.x & 63;
    const int row  = blockIdx.x * 4 + wave;
    const float4* Ar = (const float4*)(A + (size_t)row * N_NODES);
    float s = 0.f;
#pragma unroll
    for (int i = 0; i < 32; ++i) {
        float4 v = Ar[lane + 64 * i];
        s += (v.x + v.y) + (v.z + v.w);
    }
#pragma unroll
    for (int off = 32; off; off >>= 1) s += __shfl_down(s, off, 64);
    if (lane == 0) deg[row] = s;
}

__global__ __launch_bounds__(256) void k_spmm_f32(const float* __restrict__ A,
                                                  const unsigned short* __restrict__ Gp,
                                                  float* __restrict__ h2s) {
    const int lane = threadIdx.x & 63;
    const int wave = threadIdx.x >> 6;
    const int quad = lane >> 4;
    const int l15  = lane & 15;
    const int row  = blockIdx.x * 64 + wave * 16 + l15;
    const float* Ar = A + (size_t)row * N_NODES;
    const int kt0 = blockIdx.y * 32;

    f32x4 acc[4] = {};
    const short8* Gq = (const short8*)Gp;

    for (int kt = kt0; kt < kt0 + 32; ++kt) {
        const float4* pa = (const float4*)(Ar + kt * 32 + quad * 8);
        float4 a0 = pa[0], a1 = pa[1];
        short8 af;
        af[0] = f2bf(a0.x); af[1] = f2bf(a0.y); af[2] = f2bf(a0.z); af[3] = f2bf(a0.w);
        af[4] = f2bf(a1.x); af[5] = f2bf(a1.y); af[6] = f2bf(a1.z); af[7] = f2bf(a1.w);
        const short8* gb = Gq + (size_t)kt * 4 * 64 + lane;
#pragma unroll
        for (int u = 0; u < 4; ++u) {
            acc[u] = __builtin_amdgcn_mfma_f32_16x16x32_bf16(af, gb[u * 64], acc[u], 0, 0, 0);
        }
    }
    float* H = h2s + (size_t)blockIdx.y * ((size_t)N_NODES * D_OUT);
    const int r0 = blockIdx.x * 64 + wave * 16 + quad * 4;
#pragma unroll
    for (int u = 0; u < 4; ++u)
#pragma unroll
        for (int r = 0; r < 4; ++r)
            H[(size_t)(r0 + r) * D_OUT + u * 16 + l15] = acc[u][r];
}

extern "C" void kernel_launch(void* const* d_in, const int* in_sizes, int n_in,
                              void* d_out, int out_size, void* d_ws, size_t ws_size,
                              hipStream_t stream) {
    const float* X = (const float*)d_in[0];   // features [8192,128]
    const float* A = (const float*)d_in[1];   // adjacency [8192,8192]
    const float* W = (const float*)d_in[2];   // weight [128,64]
    float* out = (float*)d_out;

    char* ws = (char*)d_ws;
    float*          deg = (float*)ws;                                  // 32 KB
    unsigned short* Gp  = (unsigned short*)(ws + 32768);               // 1 MB
    float*          h2s = (float*)(ws + 32768 + 1048576);              // 16 MB
    unsigned short* Ap  = (unsigned short*)(ws + 32768 + 1048576 + 16777216); // 128 MB

    const size_t need = 32768 + 1048576 + 16777216 + (size_t)N_NODES * N_NODES * 2;

    if (ws_size >= need) {
        k_degpack<<<N_NODES / 16, 256, 0, stream>>>(A, deg, Ap);
        k_gpack  <<<N_NODES / 32, 256, 0, stream>>>(X, W, deg, Gp);
        k_spmm_bf16<<<dim3(N_NODES / 64, NSPLIT), 256, 0, stream>>>(Ap, Gp, h2s);
        k_out    <<<(N_NODES * D_OUT / 4) / 256, 256, 0, stream>>>(h2s, deg, out);
    } else {
        k_deg    <<<N_NODES / 4, 256, 0, stream>>>(A, deg);
        k_gpack  <<<N_NODES / 32, 256, 0, stream>>>(X, W, deg, Gp);
        k_spmm_f32<<<dim3(N_NODES / 64, NSPLIT), 256, 0, stream>>>(A, Gp, h2s);
        k_out    <<<(N_NODES * D_OUT / 4) / 256, 256, 0, stream>>>(h2s, deg, out);
    }
}